// Round 11
// baseline (210.414 us; speedup 1.0000x reference)
//
#include <hip/hip_runtime.h>
#include <hip/hip_bf16.h>
#include <stdint.h>

// Correlation (FlowNet), md=4: out[b, di*9+dj, h, w] = sum_c x[b,c,h,w]*yp[b,c,h+di-4,w+dj-4] / 256
// R10 = R9 champion with CHUNK 32 -> 64: half the per-block HBM-stall events (4
// iterations), 2x longer compute phases, half the barriers. y-only LDS 16 rows x
// 4KB = 64KB (single buffer); x moves to global-direct (16 dwords/lane/chunk,
// L1/L2-resident). All other machinery identical to R9.

using f32x4 = __attribute__((ext_vector_type(4))) float;
using s16x4 = __attribute__((ext_vector_type(4))) short;
using u16x4 = __attribute__((ext_vector_type(4))) unsigned short;

#define C_DIM 256
#define H_DIM 96
#define W_DIM 192
#define HWSZ  (H_DIM * W_DIM)
#define MD 4
#define KD 9
#define CHUNK 64
#define NCHUNK 4
#define HR 8
#define NTHR 512
#define WTILES 12          // 192/16
#define HQ 12              // 96/8
#define SUB_B 128          // [4c][16s] bf16 subtile = 128B, aligned (tr native)
#define YROW_B (32 * SUB_B)   // 2 s-tiles x 16 cg subtiles = 4096B per y row (64c)
#define LDS_BYTES (16 * YROW_B)  // 65536
#define NYQ (16 * CHUNK * 6)     // 6144 staged 16B-quads per chunk = 12/thread

static __device__ __forceinline__ unsigned short bf16b(float f) {
  __bf16 h = (__bf16)f;                   // RNE
  unsigned short s; __builtin_memcpy(&s, &h, 2); return s;
}

// per-lane: reads column (l&15) of the [4c][16s] bf16 subtile at its address
static __device__ __forceinline__ s16x4 tr16(uint32_t addr) {
  s16x4 d;
  asm volatile("ds_read_b64_tr_b16 %0, %1" : "=v"(d) : "v"(addr));
  return d;
}

#define WAITLG(n) asm volatile("s_waitcnt lgkmcnt(" #n ")" ::: "memory")

__global__ __launch_bounds__(NTHR, 4)
void corr_mfma(const float* __restrict__ xg, const float* __restrict__ yg,
               float* __restrict__ outg) {
  __shared__ __align__(16) char smem[LDS_BYTES];

  const int bid = blockIdx.x;             // 1152 = 8 * 144
  const int b   = bid & 7;                // batch == XCD (round-robin dispatch)
  const int rem = bid >> 3;               // 0..143, hq fastest -> h-halo L2 reuse
  const int wt  = rem / HQ;
  const int hq  = rem - wt * HQ;
  const int w0  = wt * 16;
  const int h0  = hq * HR;

  const int tid  = threadIdx.x;
  const int lane = tid & 63;
  const int wv   = tid >> 6;              // wave id 0..7 -> output row h0+wv
  const int hi   = lane >> 4;
  const int lm   = lane & 15;

  const uint32_t sbase = (uint32_t)(uintptr_t)&smem[0];  // LDS aperture 4GB-aligned

  // ---- y staging decode, hoisted: 6144 quads = 12 per thread
  uint32_t goffY[12], loffY[12];
  uint32_t vmaskY = 0;
#pragma unroll
  for (int i = 0; i < 12; ++i) {
    const int qid = i * NTHR + tid;
    const int q = qid % 6;
    const int c = (qid / 6) % CHUNK;      // 0..63
    const int r = qid / 384;              // y row 0..15 -> h0+r-4
    const int hg = h0 + r - MD;
    const int sg = w0 - MD + 4 * q;       // 4-aligned -> OOB is whole-quad only
    const bool ok = (hg >= 0) && (hg < H_DIM) && (sg >= 0) && (sg < W_DIM);
    if (ok) vmaskY |= (1u << i);
    goffY[i] = ok ? (uint32_t)(((b * C_DIM + c) * H_DIM + hg) * W_DIM + sg) : 0u;
    const int s = 4 * q;                  // local s 0..20
    loffY[i] = r * YROW_B + (s >> 4) * (16 * SUB_B) + (c >> 2) * SUB_B
             + (c & 3) * 32 + (s & 15) * 2;
  }

  // ---- x global-direct: lane (hi,lm) needs c = c0 + kh*16 + hi*4 + e at (h, w0+lm)
  const int h = h0 + wv;
  const uint32_t xbase =
      (uint32_t)(((b * C_DIM + hi * 4) * H_DIM + h) * W_DIM + w0 + lm);

  f32x4 acc[KD][2];
#pragma unroll
  for (int di = 0; di < KD; ++di) {
    acc[di][0] = f32x4{0.f, 0.f, 0.f, 0.f};
    acc[di][1] = f32x4{0.f, 0.f, 0.f, 0.f};
  }

  // B tr base: y LDS row for (wv, di) is wv+di; s-tile adds 2048, kh adds 512
  const uint32_t bbase = sbase + (uint32_t)wv * YROW_B + hi * SUB_B + lm * 8;

  for (int t = 0; t < NCHUNK; ++t) {
    const uint32_t co = (uint32_t)t * CHUNK * HWSZ;

    // ---- y global loads + convert (stall here, before barriers - R9 order)
    u16x4 wbuf[12];
#pragma unroll
    for (int i = 0; i < 12; ++i) {
      float4 v = make_float4(0.f, 0.f, 0.f, 0.f);
      if (vmaskY & (1u << i)) v = *(const float4*)(yg + goffY[i] + co);
      wbuf[i] = u16x4{bf16b(v.x), bf16b(v.y), bf16b(v.z), bf16b(v.w)};
    }
    // ---- x loads + A-frag cvt (16 dwords; x tile is L1/L2-resident)
    s16x4 afr[4];
#pragma unroll
    for (int kh = 0; kh < 4; ++kh) {
      float xv0 = xg[xbase + co + (uint32_t)(kh * 16 + 0) * HWSZ];
      float xv1 = xg[xbase + co + (uint32_t)(kh * 16 + 1) * HWSZ];
      float xv2 = xg[xbase + co + (uint32_t)(kh * 16 + 2) * HWSZ];
      float xv3 = xg[xbase + co + (uint32_t)(kh * 16 + 3) * HWSZ];
      afr[kh][0] = (short)bf16b(xv0); afr[kh][1] = (short)bf16b(xv1);
      afr[kh][2] = (short)bf16b(xv2); afr[kh][3] = (short)bf16b(xv3);
    }

    __syncthreads();                      // previous chunk's LDS reads done
#pragma unroll
    for (int i = 0; i < 12; ++i) *(u16x4*)(smem + loffY[i]) = wbuf[i];
    __syncthreads();

    // ---- compute chunk t: 2-slot rotated tr reads (8/di), counted lgkm ladder
    s16x4 bsl[2][8];

#define ISSUE_DI(di) { \
    const uint32_t ba = bbase + (uint32_t)(di) * YROW_B; \
    bsl[(di) & 1][0] = tr16(ba);           /* t0 kh0 */ \
    bsl[(di) & 1][1] = tr16(ba + 512);     /* t0 kh1 */ \
    bsl[(di) & 1][2] = tr16(ba + 1024);    /* t0 kh2 */ \
    bsl[(di) & 1][3] = tr16(ba + 1536);    /* t0 kh3 */ \
    bsl[(di) & 1][4] = tr16(ba + 2048);    /* t1 kh0 */ \
    bsl[(di) & 1][5] = tr16(ba + 2560);    /* t1 kh1 */ \
    bsl[(di) & 1][6] = tr16(ba + 3072);    /* t1 kh2 */ \
    bsl[(di) & 1][7] = tr16(ba + 3584); }  /* t1 kh3 */

#define DO_DI(di, lg) \
    WAITLG(lg); __builtin_amdgcn_sched_barrier(0); \
    acc[di][0] = __builtin_amdgcn_mfma_f32_16x16x16bf16_1k(afr[0], bsl[(di) & 1][0], acc[di][0], 0, 0, 0); \
    acc[di][0] = __builtin_amdgcn_mfma_f32_16x16x16bf16_1k(afr[1], bsl[(di) & 1][1], acc[di][0], 0, 0, 0); \
    acc[di][0] = __builtin_amdgcn_mfma_f32_16x16x16bf16_1k(afr[2], bsl[(di) & 1][2], acc[di][0], 0, 0, 0); \
    acc[di][0] = __builtin_amdgcn_mfma_f32_16x16x16bf16_1k(afr[3], bsl[(di) & 1][3], acc[di][0], 0, 0, 0); \
    acc[di][1] = __builtin_amdgcn_mfma_f32_16x16x16bf16_1k(afr[0], bsl[(di) & 1][4], acc[di][1], 0, 0, 0); \
    acc[di][1] = __builtin_amdgcn_mfma_f32_16x16x16bf16_1k(afr[1], bsl[(di) & 1][5], acc[di][1], 0, 0, 0); \
    acc[di][1] = __builtin_amdgcn_mfma_f32_16x16x16bf16_1k(afr[2], bsl[(di) & 1][6], acc[di][1], 0, 0, 0); \
    acc[di][1] = __builtin_amdgcn_mfma_f32_16x16x16bf16_1k(afr[3], bsl[(di) & 1][7], acc[di][1], 0, 0, 0);

    ISSUE_DI(0)
    ISSUE_DI(1)
    DO_DI(0, 8)
    ISSUE_DI(2)
    DO_DI(1, 8)
    ISSUE_DI(3)
    DO_DI(2, 8)
    ISSUE_DI(4)
    DO_DI(3, 8)
    ISSUE_DI(5)
    DO_DI(4, 8)
    ISSUE_DI(6)
    DO_DI(5, 8)
    ISSUE_DI(7)
    DO_DI(6, 8)
    ISSUE_DI(8)
    DO_DI(7, 8)
    DO_DI(8, 0)
#undef ISSUE_DI
#undef DO_DI
  }

  // ---- epilogue: D[m][n]: n=lm, m=hi*4+rg (verified). dj = tt*16 + lm - m.
  const float scale = 1.f / 256.f;
#pragma unroll
  for (int di = 0; di < KD; ++di) {
#pragma unroll
    for (int tt = 0; tt < 2; ++tt) {
#pragma unroll
      for (int rg = 0; rg < 4; ++rg) {
        const int m = hi * 4 + rg;
        const int dj = tt * 16 + lm - m;
        if (0 <= dj && dj <= 8) {
          outg[((b * (KD * KD) + di * KD + dj) * H_DIM + h) * W_DIM + w0 + m] =
              acc[di][tt][rg] * scale;
        }
      }
    }
  }
}

extern "C" void kernel_launch(void* const* d_in, const int* in_sizes, int n_in,
                              void* d_out, int out_size, void* d_ws, size_t ws_size,
                              hipStream_t stream) {
  const float* x = (const float*)d_in[0];
  const float* y = (const float*)d_in[1];
  float* out = (float*)d_out;
  (void)in_sizes; (void)n_in; (void)d_ws; (void)ws_size; (void)out_size;

  const int grid = 8 * HQ * WTILES;       // 1152 blocks, 512 threads
  corr_mfma<<<dim3(grid), dim3(NTHR), 0, stream>>>(x, y, out);
}

// Round 12
// 147.021 us; speedup vs baseline: 1.4312x; 1.4312x over previous
//
#include <hip/hip_runtime.h>
#include <hip/hip_bf16.h>
#include <stdint.h>

// Correlation (FlowNet), md=4: out[b, di*9+dj, h, w] = sum_c x[b,c,h,w]*yp[b,c,h+di-4,w+dj-4] / 256
// R11: PACKED-PAIR formulation. MFMA M-dim = 2 h-rows x 8 w; one B y-row r yields
// band cells (m=(j,w), n=s): di = r-j, dj = n-w. 8w x 9dj fills N=16 exactly ->
// 50.6% MFMA efficiency vs 28% (3.6x fewer MFMAs, acc 72->40 regs).
// Wave = (pair p 0..3, w-half wh 0..1). y staged per row in TWO 8-shifted
// phasings (s -4..11 / 4..19) so each wh reads 128B-aligned tr subtiles.
// Schedule/order identical to R9 champion: load+cvt -> sync -> write -> sync -> compute.

using f32x4 = __attribute__((ext_vector_type(4))) float;
using s16x4 = __attribute__((ext_vector_type(4))) short;
using u16x4 = __attribute__((ext_vector_type(4))) unsigned short;

#define C_DIM 256
#define H_DIM 96
#define W_DIM 192
#define HWSZ  (H_DIM * W_DIM)
#define MD 4
#define KD 9
#define CHUNK 32
#define NCHUNK 8
#define HR 8
#define NTHR 512
#define WTILES 12          // 192/16
#define HQ 12              // 96/8
#define YROW_B 2048        // 8 cg x (2 phasings x 128B) per y row (32c)
#define XBASE  (16 * YROW_B)            // 32768
#define LDS_BYTES (XBASE + 8 * 1024)    // + 8 (p,wh) A-units x 1024B = 40960
#define NSLOT 10           // per-thread staging slots: 8 y + 2 x

static __device__ __forceinline__ unsigned short bf16b(float f) {
  __bf16 h = (__bf16)f;                   // RNE
  unsigned short s; __builtin_memcpy(&s, &h, 2); return s;
}

// per-lane: reads column (addr&127)/8 of the 128B [4c][16m] bf16 subtile at addr
static __device__ __forceinline__ s16x4 tr16(uint32_t addr) {
  s16x4 d;
  asm volatile("ds_read_b64_tr_b16 %0, %1" : "=v"(d) : "v"(addr));
  return d;
}

#define WAITLG(n) asm volatile("s_waitcnt lgkmcnt(" #n ")" ::: "memory")

__global__ __launch_bounds__(NTHR, 4)
void corr_mfma(const float* __restrict__ xg, const float* __restrict__ yg,
               float* __restrict__ outg) {
  __shared__ __align__(16) char smem[LDS_BYTES];

  const int bid = blockIdx.x;             // 1152 = 8 * 144
  const int b   = bid & 7;                // batch == XCD (round-robin dispatch)
  const int rem = bid >> 3;               // hq fastest -> h-halo L2 reuse
  const int wt  = rem / HQ;
  const int hq  = rem - wt * HQ;
  const int w0  = wt * 16;
  const int h0  = hq * HR;

  const int tid  = threadIdx.x;
  const int lane = tid & 63;
  const int wv   = tid >> 6;              // 0..7
  const int p    = wv >> 1;               // h-pair: rows h0+2p, h0+2p+1
  const int wh   = wv & 1;                // w-half: w0+8*wh
  const int hi   = lane >> 4;
  const int lm   = lane & 15;

  const uint32_t sbase = (uint32_t)(uintptr_t)&smem[0];

  // ---- staging decode, hoisted: 5120 slots = 10/thread (8 y + 2 x).
  // y slot: row r 0..15 (y row h0+r-4), c 0..31, phasing ph (s-origin -4+8ph), q' 0..3.
  // x slot: h-row r8 0..7, c 0..31, quad q 0..3 -> A-unit (p=r8>>1, wh=q>>1).
  uint32_t goff[NSLOT], loff[NSLOT];
  uint32_t vmask = 0;
#pragma unroll
  for (int i = 0; i < NSLOT; ++i) {
    const int sid = i * NTHR + tid;
    if (i < 8) {                          // y slots (sid < 4096)
      const int r  = sid >> 8;            // 0..15
      const int u  = sid & 255;
      const int c  = u >> 3;              // 0..31
      const int ph = (u >> 2) & 1;
      const int qp = u & 3;
      const int hg = h0 + r - MD;
      const int sg = w0 - MD + 8 * ph + 4 * qp;   // 4-aligned: OOB whole-quad
      const bool ok = (hg >= 0) && (hg < H_DIM) && (sg >= 0) && (sg + 3 < W_DIM);
      if (ok) vmask |= (1u << i);
      goff[i] = ok ? (uint32_t)(((b * C_DIM + c) * H_DIM + hg) * W_DIM + sg) : 0u;
      loff[i] = r * YROW_B + (c >> 2) * 256 + ph * 128 + (c & 3) * 32 + qp * 8;
    } else {                              // x slots
      const int v  = sid - 4096;          // 0..1023
      const int r8 = v >> 7;              // 0..7
      const int u  = v & 127;
      const int c  = u >> 2;
      const int q  = u & 3;               // w-quad: w0+4q
      vmask |= (1u << i);
      goff[i] = (uint32_t)(((b * C_DIM + c) * H_DIM + (h0 + r8)) * W_DIM + (w0 + 4 * q));
      loff[i] = XBASE + ((r8 >> 1) * 2 + (q >> 1)) * 1024 + (c >> 2) * 128
              + (c & 3) * 32 + ((r8 & 1) * 8 + (q & 1) * 4) * 2;
    }
  }

  f32x4 acc[10];
#pragma unroll
  for (int r = 0; r < 10; ++r) acc[r] = f32x4{0.f, 0.f, 0.f, 0.f};

  // A base: unit (p,wh), subtile cg = kh*4+hi (kh adds 512), col m = lm
  const uint32_t abase = sbase + XBASE + (uint32_t)(p * 2 + wh) * 1024 + hi * 128 + lm * 8;
  // B base: y LDS row (2p + r), cg = kh*4+hi at 256B (kh adds 1024), phasing wh
  const uint32_t bbase = sbase + (uint32_t)(2 * p) * YROW_B + hi * 256 + wh * 128 + lm * 8;

  for (int t = 0; t < NCHUNK; ++t) {
    const uint32_t co = (uint32_t)t * CHUNK * HWSZ;

    // ---- global loads + cvt (R9 order: stall here, before barriers)
    u16x4 wbuf[NSLOT];
#pragma unroll
    for (int i = 0; i < NSLOT; ++i) {
      float4 v = make_float4(0.f, 0.f, 0.f, 0.f);
      if (i < 8) {
        if (vmask & (1u << i)) v = *(const float4*)(yg + goff[i] + co);
      } else {
        v = *(const float4*)(xg + goff[i] + co);
      }
      wbuf[i] = u16x4{bf16b(v.x), bf16b(v.y), bf16b(v.z), bf16b(v.w)};
    }

    __syncthreads();                      // previous chunk's LDS reads done
#pragma unroll
    for (int i = 0; i < NSLOT; ++i) *(u16x4*)(smem + loff[i]) = wbuf[i];
    __syncthreads();

    // ---- compute: A frags + 10 B-rows, 2-slot rotated, counted lgkm ladder
    s16x4 afr0 = tr16(abase);
    s16x4 afr1 = tr16(abase + 512);
    s16x4 bsl[2][2];

#define ISSUE_R(r) { \
    const uint32_t ba = bbase + (uint32_t)(r) * YROW_B; \
    bsl[(r) & 1][0] = tr16(ba); \
    bsl[(r) & 1][1] = tr16(ba + 1024); }

#define DO_R(r, lg) \
    WAITLG(lg); __builtin_amdgcn_sched_barrier(0); \
    acc[r] = __builtin_amdgcn_mfma_f32_16x16x16bf16_1k(afr0, bsl[(r) & 1][0], acc[r], 0, 0, 0); \
    acc[r] = __builtin_amdgcn_mfma_f32_16x16x16bf16_1k(afr1, bsl[(r) & 1][1], acc[r], 0, 0, 0);

    __builtin_amdgcn_s_setprio(1);
    ISSUE_R(0)
    ISSUE_R(1)
    DO_R(0, 2)   // A + B0 done (only B1 pair may be outstanding)
    ISSUE_R(2)
    DO_R(1, 2)
    ISSUE_R(3)
    DO_R(2, 2)
    ISSUE_R(4)
    DO_R(3, 2)
    ISSUE_R(5)
    DO_R(4, 2)
    ISSUE_R(6)
    DO_R(5, 2)
    ISSUE_R(7)
    DO_R(6, 2)
    ISSUE_R(8)
    DO_R(7, 2)
    ISSUE_R(9)
    DO_R(8, 2)
    DO_R(9, 0)
    __builtin_amdgcn_s_setprio(0);
#undef ISSUE_R
#undef DO_R
  }

  // ---- epilogue: D[m][n]: m = hi*4+rg = (j<<3)|w, n = lm = s_local.
  // di = r - j, dj = lm - w; valid iff both in [0,9).
  const float scale = 1.f / 256.f;
#pragma unroll
  for (int r = 0; r < 10; ++r) {
#pragma unroll
    for (int rg = 0; rg < 4; ++rg) {
      const int m = hi * 4 + rg;
      const int j = m >> 3;
      const int w = m & 7;
      const int di = r - j;
      const int dj = lm - w;
      if (0 <= di && di < KD && 0 <= dj && dj < KD) {
        outg[((b * (KD * KD) + di * KD + dj) * H_DIM + (h0 + 2 * p + j)) * W_DIM
             + (w0 + 8 * wh + w)] = acc[r][rg] * scale;
      }
    }
  }
}

extern "C" void kernel_launch(void* const* d_in, const int* in_sizes, int n_in,
                              void* d_out, int out_size, void* d_ws, size_t ws_size,
                              hipStream_t stream) {
  const float* x = (const float*)d_in[0];
  const float* y = (const float*)d_in[1];
  float* out = (float*)d_out;
  (void)in_sizes; (void)n_in; (void)d_ws; (void)ws_size; (void)out_size;

  const int grid = 8 * HQ * WTILES;       // 1152 blocks, 512 threads
  corr_mfma<<<dim3(grid), dim3(NTHR), 0, stream>>>(x, y, out);
}